// Round 2
// baseline (391.018 us; speedup 1.0000x reference)
//
#include <hip/hip_runtime.h>
#include <math.h>

// Problem constants (fixed by setup_inputs)
#define NB 4
#define NH 64
#define NW 64
#define NS 64            // samples per ray
#define HID 128
#define POS_IN 63
#define DIR_IN 27
#define TOTAL_PARAMS 8789
// param offsets per batch row
#define OFF_POSW 0       // 128*63
#define OFF_POSB 8064    // 128
#define OFF_SIGW 8192    // 128
#define OFF_SIGB 8320    // 1
#define OFF_COLW 8321    // 3*155
#define OFF_COLB 8786    // 3

// Accurate sin/cos of a (possibly large, |arg| < ~2^14 rad) fp32 argument.
// Cody-Waite: pi = PI_HI(8-bit mantissa, exact) + PI_MID(11-bit) + PI_LO.
// n up to ~2^13 -> n*PI_HI and n*PI_MID products are exact in fp32.
__device__ __forceinline__ void sincos_acc(float arg, float& s, float& c) {
    const float INV_PI = 0.31830988618379067f;
    float nf = rintf(arg * INV_PI);
    float r = fmaf(nf, -3.140625f, arg);        // PI_HI = 201/64, 8-bit mantissa
    r = fmaf(nf, -9.675025940e-4f, r);          // PI_MID, 11-bit mantissa
    r = fmaf(nf, -1.509957880e-7f, r);          // PI_LO
    float ss = __sinf(r);                       // |r| <= pi/2: accurate
    float cc = __cosf(r);
    int n = (int)nf;
    if (n & 1) { ss = -ss; cc = -cc; }
    s = ss; c = cc;
}

// Pin waves/EU to exactly 4 -> 128-VGPR budget. With the default
// __launch_bounds__(256,4) range [4,8] the allocator chased 8 waves/EU
// (64 VGPR) and spilled pe[64] to scratch (round-1: VGPR=64, ~3x VALU bloat).
__attribute__((amdgpu_flat_work_group_size(256, 256), amdgpu_waves_per_eu(4, 4)))
__global__ void nerf_render_kernel(const float* __restrict__ params,
                                   const float* __restrict__ poses,
                                   const float* __restrict__ Ks,
                                   float* __restrict__ out)
{
    // LDS staging of per-batch MLP weights.
    __shared__ float wlds[HID * 64];     // pos_w padded 63->64, row h at h*64, pad=0
    __shared__ float comb[HID * 4];      // [h][4] = {sig_w[h], col_w[0][h], col_w[1][h], col_w[2][h]}
    __shared__ float posb[HID];
    __shared__ float cwd[DIR_IN * 3 + 3]; // col_w dir part: [k][c], k=0..26
    __shared__ float extra[4];           // sig_b, col_b[0..2]

    const int tid  = threadIdx.x;
    const int lane = tid & 63;                   // sample index along ray
    const int ray  = blockIdx.x * 4 + (tid >> 6);
    const int b    = ray >> 12;                  // 4096 rays per batch
    const int p    = ray & 4095;                 // pixel index i*W+j
    const int i    = p >> 6;
    const int j    = p & 63;

    const float* pb = params + b * TOTAL_PARAMS;

    // ---- stage weights to LDS ----
    for (int k = tid; k < HID * POS_IN; k += 256) {
        int h = k / 63, d = k - h * 63;
        wlds[h * 64 + d] = pb[OFF_POSW + k];
    }
    if (tid < HID) {
        wlds[tid * 64 + 63] = 0.0f;              // zero pad (poison-safe)
        posb[tid] = pb[OFF_POSB + tid];
        comb[tid * 4 + 0] = pb[OFF_SIGW + tid];
    }
    for (int k = tid; k < 3 * 155; k += 256) {
        int c = k / 155, q = k - c * 155;
        float v = pb[OFF_COLW + k];
        if (q < HID) comb[q * 4 + 1 + c] = v;
        else cwd[(q - HID) * 3 + c] = v;
    }
    if (tid == 0) extra[0] = pb[OFF_SIGB];
    if (tid < 3) extra[1 + tid] = pb[OFF_COLB + tid];
    __syncthreads();

    // ---- ray setup ----
    const float* Kb = Ks + b * 9;
    float fx = Kb[0], cx = Kb[2], fy = Kb[4], cy = Kb[5];
    const float* Pb = poses + b * 16;
    float dcx = ((float)j - cx) / fx;
    float dcy = -(((float)i - cy) / fy);
    float dcz = -1.0f;
    float dx = Pb[0] * dcx + Pb[1] * dcy + Pb[2]  * dcz;
    float dy = Pb[4] * dcx + Pb[5] * dcy + Pb[6]  * dcz;
    float dz = Pb[8] * dcx + Pb[9] * dcy + Pb[10] * dcz;
    float ox = Pb[3], oy = Pb[7], oz = Pb[11];

    float t0 = (float)lane * (1.0f / 63.0f);
    float z  = 0.1f * (1.0f - t0) + 10.0f * t0;
    float t1 = (float)(lane + 1) * (1.0f / 63.0f);
    float z1 = 0.1f * (1.0f - t1) + 10.0f * t1;
    float dist = (lane == 63) ? 1e10f : (z1 - z);

    float px = ox + dx * z, py = oy + dy * z, pz = oz + dz * z;

    // ---- positional encoding into registers (compile-time indices only) ----
    const float PI_F = 3.14159274101257324f;     // fl(pi), matches jnp weak-typed pi
    float pe[64];
    pe[0] = px; pe[1] = py; pe[2] = pz;
    pe[63] = 0.0f;
    #pragma unroll
    for (int f = 0; f < 10; f++) {
        float freq = PI_F * (float)(1 << f);     // exact pow2 scaling = reference freqs
        float s0, c0, s1, c1, s2, c2;
        sincos_acc(px * freq, s0, c0);
        sincos_acc(py * freq, s1, c1);
        sincos_acc(pz * freq, s2, c2);
        pe[3 + f * 6 + 0] = s0; pe[3 + f * 6 + 1] = s1; pe[3 + f * 6 + 2] = s2;
        pe[3 + f * 6 + 3] = c0; pe[3 + f * 6 + 4] = c1; pe[3 + f * 6 + 5] = c2;
    }

    // ---- color accumulators: bias + direction-encoding part (shared per ray) ----
    float cacc0 = extra[1], cacc1 = extra[2], cacc2 = extra[3];
    {
        float dvx = dx, dvy = dy, dvz = dz;
        cacc0 += cwd[0] * dvx + cwd[3] * dvy + cwd[6] * dvz;
        cacc1 += cwd[1] * dvx + cwd[4] * dvy + cwd[7] * dvz;
        cacc2 += cwd[2] * dvx + cwd[5] * dvy + cwd[8] * dvz;
        #pragma unroll
        for (int f = 0; f < 4; f++) {
            float freq = PI_F * (float)(1 << f);
            float sv[3], cv[3];
            sincos_acc(dvx * freq, sv[0], cv[0]);
            sincos_acc(dvy * freq, sv[1], cv[1]);
            sincos_acc(dvz * freq, sv[2], cv[2]);
            #pragma unroll
            for (int d0 = 0; d0 < 3; d0++) {
                int ks = 3 + f * 6 + d0;
                int kc = ks + 3;
                cacc0 += cwd[ks * 3 + 0] * sv[d0];
                cacc1 += cwd[ks * 3 + 1] * sv[d0];
                cacc2 += cwd[ks * 3 + 2] * sv[d0];
                cacc0 += cwd[kc * 3 + 0] * cv[d0];
                cacc1 += cwd[kc * 3 + 1] * cv[d0];
                cacc2 += cwd[kc * 3 + 2] * cv[d0];
            }
        }
    }

    // ---- main MLP loop: 128 hidden units, weights broadcast from LDS ----
    float sacc = extra[0];
    const float4* wlds4 = (const float4*)wlds;
    const float4* comb4 = (const float4*)comb;
    for (int h = 0; h < HID; h++) {
        float4 sc = comb4[h];
        const float4* wr = wlds4 + h * 16;
        float a0 = posb[h], a1 = 0.0f, a2 = 0.0f, a3 = 0.0f;  // 4 chains for ILP
        #pragma unroll
        for (int q = 0; q < 16; q++) {
            float4 w4 = wr[q];
            a0 = fmaf(w4.x, pe[q * 4 + 0], a0);
            a1 = fmaf(w4.y, pe[q * 4 + 1], a1);
            a2 = fmaf(w4.z, pe[q * 4 + 2], a2);
            a3 = fmaf(w4.w, pe[q * 4 + 3], a3);
        }
        float hv = fmaxf((a0 + a1) + (a2 + a3), 0.0f);
        sacc  = fmaf(sc.x, hv, sacc);
        cacc0 = fmaf(sc.y, hv, cacc0);
        cacc1 = fmaf(sc.z, hv, cacc1);
        cacc2 = fmaf(sc.w, hv, cacc2);
    }

    // ---- volume rendering: wave-level scan over the 64 samples of this ray ----
    float alpha = 1.0f - expf(-fmaxf(sacc, 0.0f) * dist);
    float tr = 1.0f - alpha + 1e-10f;
    float prod = tr;
    #pragma unroll
    for (int off = 1; off < 64; off <<= 1) {
        float up = __shfl_up(prod, off);
        if (lane >= off) prod *= up;
    }
    float T = __shfl_up(prod, 1);
    if (lane == 0) T = 1.0f;
    float w = alpha * T;

    float r = 1.0f / (1.0f + expf(-cacc0));
    float g = 1.0f / (1.0f + expf(-cacc1));
    float bl = 1.0f / (1.0f + expf(-cacc2));

    float wr_ = w * r, wg_ = w * g, wb_ = w * bl, wz_ = w * z, wa_ = w;
    #pragma unroll
    for (int off = 32; off >= 1; off >>= 1) {
        wr_ += __shfl_xor(wr_, off);
        wg_ += __shfl_xor(wg_, off);
        wb_ += __shfl_xor(wb_, off);
        wz_ += __shfl_xor(wz_, off);
        wa_ += __shfl_xor(wa_, off);
    }

    if (lane == 0) {
        float bg = 1.0f - wa_;
        // rgb_img: [B,3,H,W] then depth [B,1,H,W] then acc [B,1,H,W], flat
        out[(b * 3 + 0) * 4096 + p] = wr_ + bg;
        out[(b * 3 + 1) * 4096 + p] = wg_ + bg;
        out[(b * 3 + 2) * 4096 + p] = wb_ + bg;
        out[NB * 3 * 4096 + b * 4096 + p] = wz_;
        out[NB * 4 * 4096 + b * 4096 + p] = wa_;
    }
}

extern "C" void kernel_launch(void* const* d_in, const int* in_sizes, int n_in,
                              void* d_out, int out_size, void* d_ws, size_t ws_size,
                              hipStream_t stream) {
    const float* params = (const float*)d_in[0];
    const float* poses  = (const float*)d_in[1];
    const float* Ks     = (const float*)d_in[2];
    float* out = (float*)d_out;
    // 4 batches * 4096 rays / 4 rays-per-block = 4096 blocks, 256 threads
    nerf_render_kernel<<<dim3(4096), dim3(256), 0, stream>>>(params, poses, Ks, out);
}

// Round 4
// 345.918 us; speedup vs baseline: 1.1304x; 1.1304x over previous
//
#include <hip/hip_runtime.h>
#include <math.h>

// Problem constants (fixed by setup_inputs)
#define NB 4
#define NS 64            // samples per ray
#define HID 128
#define POS_IN 63
#define DIR_IN 27
#define TOTAL_PARAMS 8789
// param offsets per batch row
#define OFF_POSW 0       // 128*63
#define OFF_POSB 8064    // 128
#define OFF_SIGW 8192    // 128
#define OFF_SIGB 8320    // 1
#define OFF_COLW 8321    // 3*155
#define OFF_COLB 8786    // 3

// Accurate sin/cos of a (possibly large, |arg| < ~2^14 rad) fp32 argument.
// Cody-Waite: pi = PI_HI(8-bit mantissa, exact) + PI_MID(11-bit) + PI_LO.
__device__ __forceinline__ void sincos_acc(float arg, float& s, float& c) {
    const float INV_PI = 0.31830988618379067f;
    float nf = rintf(arg * INV_PI);
    float r = fmaf(nf, -3.140625f, arg);        // PI_HI = 201/64, 8-bit mantissa
    r = fmaf(nf, -9.675025940e-4f, r);          // PI_MID, 11-bit mantissa
    r = fmaf(nf, -1.509957880e-7f, r);          // PI_LO
    float ss = __sinf(r);
    float cc = __cosf(r);
    int n = (int)nf;
    if (n & 1) { ss = -ss; cc = -cc; }
    s = ss; c = cc;
}

// All MLP weights are wave-uniform -> read them through the SCALAR path
// (s_load via readfirstlane'd pointer), keeping pe[] in VGPRs and weights in
// SGPRs. No LDS at all. Pin 4 waves/EU (128-reg unified budget) so the
// allocator doesn't shelve pe into AGPRs (round-2: 64 VGPR + 64 AGPR ->
// v_accvgpr_read per FMA operand, ~2x VALU bloat).
__attribute__((amdgpu_flat_work_group_size(256, 256), amdgpu_waves_per_eu(4, 4)))
__global__ void nerf_render_kernel(const float* __restrict__ params,
                                   const float* __restrict__ poses,
                                   const float* __restrict__ Ks,
                                   float* __restrict__ out)
{
    const int tid  = threadIdx.x;
    const int lane = tid & 63;                   // sample index along ray
    const int ray  = blockIdx.x * 4 + (tid >> 6);
    const int b    = ray >> 12;                  // 4096 rays per batch
    const int p    = ray & 4095;                 // pixel index i*W+j
    const int i    = p >> 6;
    const int j    = p & 63;

    // Wave-uniform batch index -> scalar (SMEM) loads for every weight access.
    const int bu = __builtin_amdgcn_readfirstlane(b);
    const float* __restrict__ pw = params + bu * TOTAL_PARAMS;

    // ---- ray setup ----
    const float* Kb = Ks + bu * 9;
    float fx = Kb[0], cx = Kb[2], fy = Kb[4], cy = Kb[5];
    const float* Pb = poses + bu * 16;
    float dcx = ((float)j - cx) / fx;
    float dcy = -(((float)i - cy) / fy);
    float dcz = -1.0f;
    float dx = Pb[0] * dcx + Pb[1] * dcy + Pb[2]  * dcz;
    float dy = Pb[4] * dcx + Pb[5] * dcy + Pb[6]  * dcz;
    float dz = Pb[8] * dcx + Pb[9] * dcy + Pb[10] * dcz;
    float ox = Pb[3], oy = Pb[7], oz = Pb[11];

    float t0 = (float)lane * (1.0f / 63.0f);
    float z  = 0.1f * (1.0f - t0) + 10.0f * t0;
    float t1 = (float)(lane + 1) * (1.0f / 63.0f);
    float z1 = 0.1f * (1.0f - t1) + 10.0f * t1;
    float dist = (lane == 63) ? 1e10f : (z1 - z);

    float px = ox + dx * z, py = oy + dy * z, pz = oz + dz * z;

    // ---- positional encoding into registers (compile-time indices only) ----
    const float PI_F = 3.14159274101257324f;     // fl(pi), matches jnp pi
    float pe[63];
    pe[0] = px; pe[1] = py; pe[2] = pz;
    #pragma unroll
    for (int f = 0; f < 10; f++) {
        float freq = PI_F * (float)(1 << f);
        float s0, c0, s1, c1, s2, c2;
        sincos_acc(px * freq, s0, c0);
        sincos_acc(py * freq, s1, c1);
        sincos_acc(pz * freq, s2, c2);
        pe[3 + f * 6 + 0] = s0; pe[3 + f * 6 + 1] = s1; pe[3 + f * 6 + 2] = s2;
        pe[3 + f * 6 + 3] = c0; pe[3 + f * 6 + 4] = c1; pe[3 + f * 6 + 5] = c2;
    }

    // ---- color accumulators: bias + direction-encoding part (uniform weights) ----
    float cacc0 = pw[OFF_COLB + 0];
    float cacc1 = pw[OFF_COLB + 1];
    float cacc2 = pw[OFF_COLB + 2];
    {
        // col_w dir columns: pw[OFF_COLW + c*155 + 128 + k], k = 0..26
        const float* cw0 = pw + OFF_COLW + 0 * 155 + HID;
        const float* cw1 = pw + OFF_COLW + 1 * 155 + HID;
        const float* cw2 = pw + OFF_COLW + 2 * 155 + HID;
        cacc0 += cw0[0] * dx + cw0[1] * dy + cw0[2] * dz;
        cacc1 += cw1[0] * dx + cw1[1] * dy + cw1[2] * dz;
        cacc2 += cw2[0] * dx + cw2[1] * dy + cw2[2] * dz;
        #pragma unroll
        for (int f = 0; f < 4; f++) {
            float freq = PI_F * (float)(1 << f);
            float sv[3], cv[3];
            sincos_acc(dx * freq, sv[0], cv[0]);
            sincos_acc(dy * freq, sv[1], cv[1]);
            sincos_acc(dz * freq, sv[2], cv[2]);
            #pragma unroll
            for (int d0 = 0; d0 < 3; d0++) {
                int ks = 3 + f * 6 + d0;   // sin slot in the 27-dim dir encoding
                int kc = ks + 3;           // cos slot
                cacc0 = fmaf(cw0[ks], sv[d0], cacc0);
                cacc1 = fmaf(cw1[ks], sv[d0], cacc1);
                cacc2 = fmaf(cw2[ks], sv[d0], cacc2);
                cacc0 = fmaf(cw0[kc], cv[d0], cacc0);
                cacc1 = fmaf(cw1[kc], cv[d0], cacc1);
                cacc2 = fmaf(cw2[kc], cv[d0], cacc2);
            }
        }
    }

    // ---- main MLP loop: weights via scalar loads, pe in VGPRs ----
    float sacc = pw[OFF_SIGB];
    const float* __restrict__ posb = pw + OFF_POSB;
    const float* __restrict__ sigw = pw + OFF_SIGW;
    const float* __restrict__ colw0 = pw + OFF_COLW + 0 * 155;
    const float* __restrict__ colw1 = pw + OFF_COLW + 1 * 155;
    const float* __restrict__ colw2 = pw + OFF_COLW + 2 * 155;
    for (int h = 0; h < HID; h++) {
        const float* __restrict__ wr = pw + OFF_POSW + h * POS_IN;
        float a0 = posb[h], a1 = 0.0f, a2 = 0.0f, a3 = 0.0f;  // 4 chains (ILP)
        #pragma unroll
        for (int k = 0; k < 60; k += 4) {
            a0 = fmaf(wr[k + 0], pe[k + 0], a0);
            a1 = fmaf(wr[k + 1], pe[k + 1], a1);
            a2 = fmaf(wr[k + 2], pe[k + 2], a2);
            a3 = fmaf(wr[k + 3], pe[k + 3], a3);
        }
        a0 = fmaf(wr[60], pe[60], a0);
        a1 = fmaf(wr[61], pe[61], a1);
        a2 = fmaf(wr[62], pe[62], a2);
        float hv = fmaxf((a0 + a1) + (a2 + a3), 0.0f);
        sacc  = fmaf(sigw[h],  hv, sacc);
        cacc0 = fmaf(colw0[h], hv, cacc0);
        cacc1 = fmaf(colw1[h], hv, cacc1);
        cacc2 = fmaf(colw2[h], hv, cacc2);
    }

    // ---- volume rendering: wave-level scan over the 64 samples of this ray ----
    float alpha = 1.0f - expf(-fmaxf(sacc, 0.0f) * dist);
    float tr = 1.0f - alpha + 1e-10f;
    float prod = tr;
    #pragma unroll
    for (int off = 1; off < 64; off <<= 1) {
        float up = __shfl_up(prod, off);
        if (lane >= off) prod *= up;
    }
    float T = __shfl_up(prod, 1);
    if (lane == 0) T = 1.0f;
    float w = alpha * T;

    float r = 1.0f / (1.0f + expf(-cacc0));
    float g = 1.0f / (1.0f + expf(-cacc1));
    float bl = 1.0f / (1.0f + expf(-cacc2));

    float wr_ = w * r, wg_ = w * g, wb_ = w * bl, wz_ = w * z, wa_ = w;
    #pragma unroll
    for (int off = 32; off >= 1; off >>= 1) {
        wr_ += __shfl_xor(wr_, off);
        wg_ += __shfl_xor(wg_, off);
        wb_ += __shfl_xor(wb_, off);
        wz_ += __shfl_xor(wz_, off);
        wa_ += __shfl_xor(wa_, off);
    }

    if (lane == 0) {
        float bg = 1.0f - wa_;
        // out layout: rgb [B,3,H,W], depth [B,1,H,W], acc [B,1,H,W], flat
        out[(b * 3 + 0) * 4096 + p] = wr_ + bg;
        out[(b * 3 + 1) * 4096 + p] = wg_ + bg;
        out[(b * 3 + 2) * 4096 + p] = wb_ + bg;
        out[NB * 3 * 4096 + b * 4096 + p] = wz_;
        out[NB * 4 * 4096 + b * 4096 + p] = wa_;
    }
}

extern "C" void kernel_launch(void* const* d_in, const int* in_sizes, int n_in,
                              void* d_out, int out_size, void* d_ws, size_t ws_size,
                              hipStream_t stream) {
    const float* params = (const float*)d_in[0];
    const float* poses  = (const float*)d_in[1];
    const float* Ks     = (const float*)d_in[2];
    float* out = (float*)d_out;
    // 4 batches * 4096 rays / 4 rays-per-block = 4096 blocks, 256 threads
    nerf_render_kernel<<<dim3(4096), dim3(256), 0, stream>>>(params, poses, Ks, out);
}

// Round 6
// 223.787 us; speedup vs baseline: 1.7473x; 1.5457x over previous
//
#include <hip/hip_runtime.h>
#include <math.h>

// Problem constants (fixed by setup_inputs)
#define NB 4
#define HID 128
#define POS_IN 63
#define TOTAL_PARAMS 8789
#define OFF_POSW 0       // 128*63
#define OFF_POSB 8064    // 128
#define OFF_SIGW 8192    // 128
#define OFF_SIGB 8320    // 1
#define OFF_COLW 8321    // 3*155
#define OFF_COLB 8786    // 3

// LDS layout in u32 units:
//  W-frags [0,8192):    slot((n0*2+s)*2+p)*256 + l*4 + e2   (B-fragments, hi/lo)
//  A-frags [8192,16384): slot(m*2+p)*256 + l*4 + e2          (half-K, double-pass)
//  samples [16384,17664): (wave*64+sample)*5 + {sig,c0,c1,c2,pad}
#define WOFF 0
#define AOFF 8192
#define SOFF 16384

typedef float        f32x4 __attribute__((ext_vector_type(4)));
typedef short        s16x8 __attribute__((ext_vector_type(8)));
typedef unsigned int u32x4 __attribute__((ext_vector_type(4)));

// Accurate sin/cos (Cody-Waite reduction), |arg| < ~2^14 rad.
__device__ __forceinline__ void sincos_acc(float arg, float& s, float& c) {
    const float INV_PI = 0.31830988618379067f;
    float nf = rintf(arg * INV_PI);
    float r = fmaf(nf, -3.140625f, arg);
    r = fmaf(nf, -9.675025940e-4f, r);
    r = fmaf(nf, -1.509957880e-7f, r);
    float ss = __sinf(r);
    float cc = __cosf(r);
    int n = (int)nf;
    if (n & 1) { ss = -ss; cc = -cc; }
    s = ss; c = cc;
}

__device__ __forceinline__ unsigned short bf16_rne(float x) {
    unsigned int u = __builtin_bit_cast(unsigned int, x);
    return (unsigned short)((u + 0x7FFFu + ((u >> 16) & 1u)) >> 16);
}
__device__ __forceinline__ float bf16_f(unsigned short h) {
    unsigned int u = ((unsigned int)h) << 16;
    return __builtin_bit_cast(float, u);
}
// split x into hi+lo bf16 (Markidis); pack pairs (x0,x1) into u32s (low = even elem)
__device__ __forceinline__ void split_pack(float x0, float x1, unsigned int& hi, unsigned int& lo) {
    unsigned short h0 = bf16_rne(x0), h1 = bf16_rne(x1);
    unsigned short l0 = bf16_rne(x0 - bf16_f(h0)), l1 = bf16_rne(x1 - bf16_f(h1));
    hi = (unsigned int)h0 | ((unsigned int)h1 << 16);
    lo = (unsigned int)l0 | ((unsigned int)l1 << 16);
}

// block=256 (4 waves = 4 rays = 256 points = 16 MFMA M-tiles). LDS 70656B ->
// 2 blocks/CU. waves_per_eu(2,2): 256-reg budget so acc[4][8] (128 AGPR) +
// ~100 arch VGPR fit without scratch.
__attribute__((amdgpu_flat_work_group_size(256, 256), amdgpu_waves_per_eu(2, 2)))
__global__ void nerf_render_kernel(const float* __restrict__ params,
                                   const float* __restrict__ poses,
                                   const float* __restrict__ Ks,
                                   float* __restrict__ out)
{
    __shared__ unsigned int lds[17664];

    const int tid  = threadIdx.x;
    const int lane = tid & 63;                 // sample index along this wave's ray
    const int w    = tid >> 6;                 // wave id = ray-local id
    const int ray  = blockIdx.x * 4 + w;
    const int b    = ray >> 12;                // 4096 rays per batch (block never crosses batch)
    const int p    = ray & 4095;
    const int i    = p >> 6;
    const int j    = p & 63;

    const float* __restrict__ pw = params + b * TOTAL_PARAMS;

    // ================= Phase 0: stage weight B-fragments (hi/lo) =================
    // B[k][n] = pos_w[n][k]; fragment: lane l holds k=(s*32+(l>>4)*8+e), n=n0*16+(l&15)
    for (int it = 0; it < 16; ++it) {
        int idx = tid + it * 256;              // 4096 units: (n0,s,l,e2)
        int e2 = idx & 3;
        int l  = (idx >> 2) & 63;
        int s  = (idx >> 8) & 1;
        int n0 = idx >> 9;
        int k0 = s * 32 + ((l >> 4) << 3) + e2 * 2;
        int n  = n0 * 16 + (l & 15);
        float w0 = pw[OFF_POSW + n * 63 + k0];             // k0 <= 62 always
        float w1 = (k0 + 1 < 63) ? pw[OFF_POSW + n * 63 + k0 + 1] : 0.0f;
        unsigned int hi, lo;
        split_pack(w0, w1, hi, lo);
        int base = ((n0 * 2 + s) * 2) * 256 + l * 4 + e2;
        lds[WOFF + base]       = hi;
        lds[WOFF + base + 256] = lo;
    }

    // ================= Phase 1: ray setup + posenc + dir-encoding =================
    const float* Kb = Ks + b * 9;
    float fx = Kb[0], cx = Kb[2], fy = Kb[4], cy = Kb[5];
    const float* Pb = poses + b * 16;
    float dcx = ((float)j - cx) / fx;
    float dcy = -(((float)i - cy) / fy);
    float dcz = -1.0f;
    float dx = Pb[0] * dcx + Pb[1] * dcy + Pb[2]  * dcz;
    float dy = Pb[4] * dcx + Pb[5] * dcy + Pb[6]  * dcz;
    float dz = Pb[8] * dcx + Pb[9] * dcy + Pb[10] * dcz;
    float ox = Pb[3], oy = Pb[7], oz = Pb[11];

    float t0 = (float)lane * (1.0f / 63.0f);
    float z  = 0.1f * (1.0f - t0) + 10.0f * t0;
    float t1 = (float)(lane + 1) * (1.0f / 63.0f);
    float z1 = 0.1f * (1.0f - t1) + 10.0f * t1;
    float dist = (lane == 63) ? 1e10f : (z1 - z);

    float px = ox + dx * z, py = oy + dy * z, pz = oz + dz * z;

    const float PI_F = 3.14159274101257324f;
    float pe[64];
    pe[0] = px; pe[1] = py; pe[2] = pz;
    pe[63] = 0.0f;                              // K-pad
    #pragma unroll
    for (int f = 0; f < 10; f++) {
        float freq = PI_F * (float)(1 << f);
        float s0, c0, s1, c1, s2, c2;
        sincos_acc(px * freq, s0, c0);
        sincos_acc(py * freq, s1, c1);
        sincos_acc(pz * freq, s2, c2);
        pe[3 + f * 6 + 0] = s0; pe[3 + f * 6 + 1] = s1; pe[3 + f * 6 + 2] = s2;
        pe[3 + f * 6 + 3] = c0; pe[3 + f * 6 + 4] = c1; pe[3 + f * 6 + 5] = c2;
    }

    // dir-encoding contribution to colors (per-ray; kept in regs until phase 4)
    float dir0 = 0.0f, dir1 = 0.0f, dir2 = 0.0f;
    {
        const float* cw0 = pw + OFF_COLW + 0 * 155 + HID;
        const float* cw1 = pw + OFF_COLW + 1 * 155 + HID;
        const float* cw2 = pw + OFF_COLW + 2 * 155 + HID;
        dir0 += cw0[0] * dx + cw0[1] * dy + cw0[2] * dz;
        dir1 += cw1[0] * dx + cw1[1] * dy + cw1[2] * dz;
        dir2 += cw2[0] * dx + cw2[1] * dy + cw2[2] * dz;
        #pragma unroll
        for (int f = 0; f < 4; f++) {
            float freq = PI_F * (float)(1 << f);
            float sv[3], cv[3];
            sincos_acc(dx * freq, sv[0], cv[0]);
            sincos_acc(dy * freq, sv[1], cv[1]);
            sincos_acc(dz * freq, sv[2], cv[2]);
            #pragma unroll
            for (int d0 = 0; d0 < 3; d0++) {
                int ks = 3 + f * 6 + d0;
                int kc = ks + 3;
                dir0 = fmaf(cw0[ks], sv[d0], dir0);
                dir1 = fmaf(cw1[ks], sv[d0], dir1);
                dir2 = fmaf(cw2[ks], sv[d0], dir2);
                dir0 = fmaf(cw0[kc], cv[d0], dir0);
                dir1 = fmaf(cw1[kc], cv[d0], dir1);
                dir2 = fmaf(cw2[kc], cv[d0], dir2);
            }
        }
    }

    // bf16 hi/lo split of pe, packed 2/u32
    unsigned int pk_hi[32], pk_lo[32];
    #pragma unroll
    for (int kk = 0; kk < 32; ++kk)
        split_pack(pe[2 * kk], pe[2 * kk + 1], pk_hi[kk], pk_lo[kk]);

    // write A-fragments for kstep s=0 (this thread = point pt=tid, M-tile m=pt>>4)
    const int m_own = tid >> 4;
    const int c15   = tid & 15;
    #pragma unroll
    for (int q = 0; q < 4; ++q) {
        int lf = (q << 4) | c15;
        u32x4 vh = { pk_hi[q*4+0], pk_hi[q*4+1], pk_hi[q*4+2], pk_hi[q*4+3] };
        u32x4 vl = { pk_lo[q*4+0], pk_lo[q*4+1], pk_lo[q*4+2], pk_lo[q*4+3] };
        *(u32x4*)&lds[AOFF + (m_own * 2 + 0) * 256 + lf * 4] = vh;
        *(u32x4*)&lds[AOFF + (m_own * 2 + 1) * 256 + lf * 4] = vl;
    }

    __syncthreads();

    // ================= Phase 2a: MFMA, K-step 0 =================
    f32x4 acc[4][8];
    #pragma unroll
    for (int mm = 0; mm < 4; ++mm)
        #pragma unroll
        for (int n0 = 0; n0 < 8; ++n0)
            acc[mm][n0] = (f32x4){0.0f, 0.0f, 0.0f, 0.0f};

    const int l = lane;
    {
        s16x8 ah[4], al4[4];
        #pragma unroll
        for (int mm = 0; mm < 4; ++mm) {
            int m = (w << 2) | mm;
            ah[mm]  = *(const s16x8*)&lds[AOFF + (m * 2 + 0) * 256 + l * 4];
            al4[mm] = *(const s16x8*)&lds[AOFF + (m * 2 + 1) * 256 + l * 4];
        }
        #pragma unroll
        for (int n0 = 0; n0 < 8; ++n0) {
            s16x8 bh = *(const s16x8*)&lds[WOFF + ((n0 * 2 + 0) * 2 + 0) * 256 + l * 4];
            s16x8 bl = *(const s16x8*)&lds[WOFF + ((n0 * 2 + 0) * 2 + 1) * 256 + l * 4];
            #pragma unroll
            for (int mm = 0; mm < 4; ++mm) {
                acc[mm][n0] = __builtin_amdgcn_mfma_f32_16x16x32_bf16(ah[mm],  bh, acc[mm][n0], 0, 0, 0);
                acc[mm][n0] = __builtin_amdgcn_mfma_f32_16x16x32_bf16(ah[mm],  bl, acc[mm][n0], 0, 0, 0);
                acc[mm][n0] = __builtin_amdgcn_mfma_f32_16x16x32_bf16(al4[mm], bh, acc[mm][n0], 0, 0, 0);
            }
        }
    }

    __syncthreads();   // all waves done reading A(s=0)

    // rewrite A-fragments with kstep s=1
    #pragma unroll
    for (int q = 0; q < 4; ++q) {
        int lf = (q << 4) | c15;
        u32x4 vh = { pk_hi[16+q*4+0], pk_hi[16+q*4+1], pk_hi[16+q*4+2], pk_hi[16+q*4+3] };
        u32x4 vl = { pk_lo[16+q*4+0], pk_lo[16+q*4+1], pk_lo[16+q*4+2], pk_lo[16+q*4+3] };
        *(u32x4*)&lds[AOFF + (m_own * 2 + 0) * 256 + lf * 4] = vh;
        *(u32x4*)&lds[AOFF + (m_own * 2 + 1) * 256 + lf * 4] = vl;
    }

    // per-lane layer-2 weights (h = n0*16 + (l&15)), loaded once
    float pbv[8], swv[8], c0v[8], c1v[8], c2v[8];
    #pragma unroll
    for (int n0 = 0; n0 < 8; ++n0) {
        int h = n0 * 16 + (l & 15);
        pbv[n0] = pw[OFF_POSB + h];
        swv[n0] = pw[OFF_SIGW + h];
        c0v[n0] = pw[OFF_COLW + 0 * 155 + h];
        c1v[n0] = pw[OFF_COLW + 1 * 155 + h];
        c2v[n0] = pw[OFF_COLW + 2 * 155 + h];
    }

    __syncthreads();

    // ================= Phase 2b: MFMA, K-step 1 =================
    {
        s16x8 ah[4], al4[4];
        #pragma unroll
        for (int mm = 0; mm < 4; ++mm) {
            int m = (w << 2) | mm;
            ah[mm]  = *(const s16x8*)&lds[AOFF + (m * 2 + 0) * 256 + l * 4];
            al4[mm] = *(const s16x8*)&lds[AOFF + (m * 2 + 1) * 256 + l * 4];
        }
        #pragma unroll
        for (int n0 = 0; n0 < 8; ++n0) {
            s16x8 bh = *(const s16x8*)&lds[WOFF + ((n0 * 2 + 1) * 2 + 0) * 256 + l * 4];
            s16x8 bl = *(const s16x8*)&lds[WOFF + ((n0 * 2 + 1) * 2 + 1) * 256 + l * 4];
            #pragma unroll
            for (int mm = 0; mm < 4; ++mm) {
                acc[mm][n0] = __builtin_amdgcn_mfma_f32_16x16x32_bf16(ah[mm],  bh, acc[mm][n0], 0, 0, 0);
                acc[mm][n0] = __builtin_amdgcn_mfma_f32_16x16x32_bf16(ah[mm],  bl, acc[mm][n0], 0, 0, 0);
                acc[mm][n0] = __builtin_amdgcn_mfma_f32_16x16x32_bf16(al4[mm], bh, acc[mm][n0], 0, 0, 0);
            }
        }
    }

    // ================= Phase 3: bias+relu, layer 2, col-reduce, stash samples =====
    #pragma unroll
    for (int mm = 0; mm < 4; ++mm) {
        #pragma unroll
        for (int r = 0; r < 4; ++r) {
            float sp = 0.0f, p0 = 0.0f, p1 = 0.0f, p2 = 0.0f;
            #pragma unroll
            for (int n0 = 0; n0 < 8; ++n0) {
                float hv = fmaxf(acc[mm][n0][r] + pbv[n0], 0.0f);
                sp = fmaf(swv[n0], hv, sp);
                p0 = fmaf(c0v[n0], hv, p0);
                p1 = fmaf(c1v[n0], hv, p1);
                p2 = fmaf(c2v[n0], hv, p2);
            }
            #pragma unroll
            for (int ofs = 1; ofs < 16; ofs <<= 1) {
                sp += __shfl_xor(sp, ofs);
                p0 += __shfl_xor(p0, ofs);
                p1 += __shfl_xor(p1, ofs);
                p2 += __shfl_xor(p2, ofs);
            }
            if ((l & 15) == 0) {
                int sample = (mm << 4) | ((l >> 4) << 2) | r;   // = pt & 63
                int sb = SOFF + (w * 64 + sample) * 5;
                lds[sb + 0] = __builtin_bit_cast(unsigned int, sp);
                lds[sb + 1] = __builtin_bit_cast(unsigned int, p0);
                lds[sb + 2] = __builtin_bit_cast(unsigned int, p1);
                lds[sb + 3] = __builtin_bit_cast(unsigned int, p2);
            }
        }
    }

    __syncthreads();

    // ================= Phase 4: volume rendering (lane = sample) =================
    int sb = SOFF + tid * 5;
    float sigma = __builtin_bit_cast(float, lds[sb + 0]) + pw[OFF_SIGB];
    float cc0   = __builtin_bit_cast(float, lds[sb + 1]) + pw[OFF_COLB + 0] + dir0;
    float cc1   = __builtin_bit_cast(float, lds[sb + 2]) + pw[OFF_COLB + 1] + dir1;
    float cc2   = __builtin_bit_cast(float, lds[sb + 3]) + pw[OFF_COLB + 2] + dir2;

    float alpha = 1.0f - expf(-fmaxf(sigma, 0.0f) * dist);
    float tr = 1.0f - alpha + 1e-10f;
    float prod = tr;
    #pragma unroll
    for (int off = 1; off < 64; off <<= 1) {
        float up = __shfl_up(prod, off);
        if (lane >= off) prod *= up;
    }
    float T = __shfl_up(prod, 1);
    if (lane == 0) T = 1.0f;
    float wgt = alpha * T;

    float r = 1.0f / (1.0f + expf(-cc0));
    float g = 1.0f / (1.0f + expf(-cc1));
    float bl = 1.0f / (1.0f + expf(-cc2));

    float wr_ = wgt * r, wg_ = wgt * g, wb_ = wgt * bl, wz_ = wgt * z, wa_ = wgt;
    #pragma unroll
    for (int off = 32; off >= 1; off >>= 1) {
        wr_ += __shfl_xor(wr_, off);
        wg_ += __shfl_xor(wg_, off);
        wb_ += __shfl_xor(wb_, off);
        wz_ += __shfl_xor(wz_, off);
        wa_ += __shfl_xor(wa_, off);
    }

    if (lane == 0) {
        float bg = 1.0f - wa_;
        out[(b * 3 + 0) * 4096 + p] = wr_ + bg;
        out[(b * 3 + 1) * 4096 + p] = wg_ + bg;
        out[(b * 3 + 2) * 4096 + p] = wb_ + bg;
        out[NB * 3 * 4096 + b * 4096 + p] = wz_;
        out[NB * 4 * 4096 + b * 4096 + p] = wa_;
    }
}

extern "C" void kernel_launch(void* const* d_in, const int* in_sizes, int n_in,
                              void* d_out, int out_size, void* d_ws, size_t ws_size,
                              hipStream_t stream) {
    const float* params = (const float*)d_in[0];
    const float* poses  = (const float*)d_in[1];
    const float* Ks     = (const float*)d_in[2];
    float* out = (float*)d_out;
    (void)d_ws; (void)ws_size;
    nerf_render_kernel<<<dim3(4096), dim3(256), 0, stream>>>(params, poses, Ks, out);
}

// Round 7
// 192.650 us; speedup vs baseline: 2.0297x; 1.1616x over previous
//
#include <hip/hip_runtime.h>
#include <math.h>

// Problem constants (fixed by setup_inputs)
#define NB 4
#define HID 128
#define POS_IN 63
#define TOTAL_PARAMS 8789
#define OFF_POSW 0       // 128*63
#define OFF_POSB 8064    // 128
#define OFF_SIGW 8192    // 128
#define OFF_SIGB 8320    // 1
#define OFF_COLW 8321    // 3*155
#define OFF_COLB 8786    // 3

// LDS layout in u32 units:
//  W-frags [0,8192):    slot((n0*2+s)*2+p)*256 + l*4 + e2   (B-fragments, hi/lo)
//  A-frags [8192,16384): slot(m*2+p)*256 + l*4 + e2          (one k-step, double-pass)
//  samples [16384,17664): (wave*64+sample)*5 + {sig,c0,c1,c2,pad}
#define WOFF 0
#define AOFF 8192
#define SOFF 16384

typedef float        f32x4 __attribute__((ext_vector_type(4)));
typedef short        s16x8 __attribute__((ext_vector_type(8)));
typedef unsigned int u32x4 __attribute__((ext_vector_type(4)));

// Accurate sin/cos (Cody-Waite reduction), |arg| < ~2^14 rad.
__device__ __forceinline__ void sincos_acc(float arg, float& s, float& c) {
    const float INV_PI = 0.31830988618379067f;
    float nf = rintf(arg * INV_PI);
    float r = fmaf(nf, -3.140625f, arg);
    r = fmaf(nf, -9.675025940e-4f, r);
    r = fmaf(nf, -1.509957880e-7f, r);
    float ss = __sinf(r);
    float cc = __cosf(r);
    int n = (int)nf;
    if (n & 1) { ss = -ss; cc = -cc; }
    s = ss; c = cc;
}

__device__ __forceinline__ unsigned short bf16_rne(float x) {
    unsigned int u = __builtin_bit_cast(unsigned int, x);
    return (unsigned short)((u + 0x7FFFu + ((u >> 16) & 1u)) >> 16);
}
__device__ __forceinline__ float bf16_f(unsigned short h) {
    unsigned int u = ((unsigned int)h) << 16;
    return __builtin_bit_cast(float, u);
}
// split x into hi+lo bf16 (Markidis); pack pairs (x0,x1) into u32s (low = even elem)
__device__ __forceinline__ void split_pack(float x0, float x1, unsigned int& hi, unsigned int& lo) {
    unsigned short h0 = bf16_rne(x0), h1 = bf16_rne(x1);
    unsigned short l0 = bf16_rne(x0 - bf16_f(h0)), l1 = bf16_rne(x1 - bf16_f(h1));
    hi = (unsigned int)h0 | ((unsigned int)h1 << 16);
    lo = (unsigned int)l0 | ((unsigned int)l1 << 16);
}

// Pre-kernel: format pos_w into MFMA B-fragments (hi/lo, both k-steps) once per
// batch, into d_ws. Main blocks then stage W with 8 coalesced dwordx4 copies
// instead of ~400 VALU of div/mod + split_pack each.
__global__ void prep_wfrags_kernel(const float* __restrict__ params,
                                   unsigned int* __restrict__ ws)
{
    const int b = blockIdx.x;
    const float* __restrict__ pb = params + b * TOTAL_PARAMS;
    unsigned int* __restrict__ wsb = ws + b * 8192;
    const int tid = threadIdx.x;
    for (int it = 0; it < 16; ++it) {
        int idx = tid + it * 256;              // 4096 units: (n0,s,l,e2)
        int e2 = idx & 3;
        int l  = (idx >> 2) & 63;
        int s  = (idx >> 8) & 1;
        int n0 = idx >> 9;
        int k0 = s * 32 + ((l >> 4) << 3) + e2 * 2;
        int n  = n0 * 16 + (l & 15);
        float w0 = pb[OFF_POSW + n * 63 + k0];
        float w1 = (k0 + 1 < 63) ? pb[OFF_POSW + n * 63 + k0 + 1] : 0.0f;
        unsigned int hi, lo;
        split_pack(w0, w1, hi, lo);
        int base = ((n0 * 2 + s) * 2) * 256 + l * 4 + e2;
        wsb[base]       = hi;
        wsb[base + 256] = lo;
    }
}

// block=256 (4 waves = 4 rays = 256 points = 16 MFMA M-tiles). LDS 70656B ->
// 2 blocks/CU. waves_per_eu(2,2): 256-reg budget; posenc is computed in two
// halves (f0-f4 before MFMA k-step 0, f5-f9 recomputed after) so no pk array
// is live across MFMA -> no scratch spill (round-6: 238 MB WRITE_SIZE).
__attribute__((amdgpu_flat_work_group_size(256, 256), amdgpu_waves_per_eu(2, 2)))
__global__ void nerf_render_kernel(const float* __restrict__ params,
                                   const float* __restrict__ poses,
                                   const float* __restrict__ Ks,
                                   float* __restrict__ out,
                                   const unsigned int* __restrict__ ws,
                                   int use_ws)
{
    __shared__ unsigned int lds[17664];

    const int tid  = threadIdx.x;
    const int lane = tid & 63;                 // sample index along this wave's ray
    const int w    = tid >> 6;                 // wave id = ray-local id
    const int ray  = blockIdx.x * 4 + w;
    const int b    = ray >> 12;                // 4096 rays per batch (block never crosses batch)
    const int p    = ray & 4095;
    const int i    = p >> 6;
    const int j    = p & 63;

    const float* __restrict__ pw = params + b * TOTAL_PARAMS;

    // ================= Phase 0: stage weight B-fragments =================
    if (use_ws) {
        const u32x4* __restrict__ wsrc = (const u32x4*)(ws + b * 8192);
        #pragma unroll
        for (int it = 0; it < 8; ++it) {
            u32x4 v = wsrc[tid + it * 256];
            *(u32x4*)&lds[WOFF + (tid + it * 256) * 4] = v;
        }
    } else {
        for (int it = 0; it < 16; ++it) {
            int idx = tid + it * 256;
            int e2 = idx & 3;
            int l  = (idx >> 2) & 63;
            int s  = (idx >> 8) & 1;
            int n0 = idx >> 9;
            int k0 = s * 32 + ((l >> 4) << 3) + e2 * 2;
            int n  = n0 * 16 + (l & 15);
            float w0 = pw[OFF_POSW + n * 63 + k0];
            float w1 = (k0 + 1 < 63) ? pw[OFF_POSW + n * 63 + k0 + 1] : 0.0f;
            unsigned int hi, lo;
            split_pack(w0, w1, hi, lo);
            int base = ((n0 * 2 + s) * 2) * 256 + l * 4 + e2;
            lds[WOFF + base]       = hi;
            lds[WOFF + base + 256] = lo;
        }
    }

    // ================= Phase 1: ray setup + posenc half 1 + dir-encoding =========
    const float* Kb = Ks + b * 9;
    float fx = Kb[0], cx = Kb[2], fy = Kb[4], cy = Kb[5];
    const float* Pb = poses + b * 16;
    float dcx = ((float)j - cx) / fx;
    float dcy = -(((float)i - cy) / fy);
    float dcz = -1.0f;
    float dx = Pb[0] * dcx + Pb[1] * dcy + Pb[2]  * dcz;
    float dy = Pb[4] * dcx + Pb[5] * dcy + Pb[6]  * dcz;
    float dz = Pb[8] * dcx + Pb[9] * dcy + Pb[10] * dcz;
    float ox = Pb[3], oy = Pb[7], oz = Pb[11];

    float t0 = (float)lane * (1.0f / 63.0f);
    float z  = 0.1f * (1.0f - t0) + 10.0f * t0;
    float t1 = (float)(lane + 1) * (1.0f / 63.0f);
    float z1 = 0.1f * (1.0f - t1) + 10.0f * t1;
    float dist = (lane == 63) ? 1e10f : (z1 - z);

    float px = ox + dx * z, py = oy + dy * z, pz = oz + dz * z;

    const float PI_F = 3.14159274101257324f;
    const int m_own = tid >> 4;
    const int c15   = tid & 15;

    // pe[0..31] = xyz + f0..f3 (full) + f4 (s0,s1,s2,c0,c1); f4c2 carried in a reg
    float f4c2;
    {
        float pe0[32];
        pe0[0] = px; pe0[1] = py; pe0[2] = pz;
        #pragma unroll
        for (int f = 0; f < 5; f++) {
            float freq = PI_F * (float)(1 << f);
            float s0, c0, s1, c1, s2, c2;
            sincos_acc(px * freq, s0, c0);
            sincos_acc(py * freq, s1, c1);
            sincos_acc(pz * freq, s2, c2);
            int base = 3 + f * 6;
            pe0[base + 0] = s0; pe0[base + 1] = s1; pe0[base + 2] = s2;
            if (f < 4) {
                pe0[base + 3] = c0; pe0[base + 4] = c1; pe0[base + 5] = c2;
            } else {
                pe0[base + 3] = c0; pe0[base + 4] = c1; f4c2 = c2;
            }
        }
        unsigned int pkh[16], pkl[16];
        #pragma unroll
        for (int kk = 0; kk < 16; ++kk)
            split_pack(pe0[2 * kk], pe0[2 * kk + 1], pkh[kk], pkl[kk]);
        #pragma unroll
        for (int q = 0; q < 4; ++q) {
            int lf = (q << 4) | c15;
            u32x4 vh = { pkh[q*4+0], pkh[q*4+1], pkh[q*4+2], pkh[q*4+3] };
            u32x4 vl = { pkl[q*4+0], pkl[q*4+1], pkl[q*4+2], pkl[q*4+3] };
            *(u32x4*)&lds[AOFF + (m_own * 2 + 0) * 256 + lf * 4] = vh;
            *(u32x4*)&lds[AOFF + (m_own * 2 + 1) * 256 + lf * 4] = vl;
        }
    }

    // dir-encoding contribution to colors (per-ray; kept in regs until phase 4)
    float dir0 = 0.0f, dir1 = 0.0f, dir2 = 0.0f;
    {
        const float* cw0 = pw + OFF_COLW + 0 * 155 + HID;
        const float* cw1 = pw + OFF_COLW + 1 * 155 + HID;
        const float* cw2 = pw + OFF_COLW + 2 * 155 + HID;
        dir0 += cw0[0] * dx + cw0[1] * dy + cw0[2] * dz;
        dir1 += cw1[0] * dx + cw1[1] * dy + cw1[2] * dz;
        dir2 += cw2[0] * dx + cw2[1] * dy + cw2[2] * dz;
        #pragma unroll
        for (int f = 0; f < 4; f++) {
            float freq = PI_F * (float)(1 << f);
            float sv[3], cv[3];
            sincos_acc(dx * freq, sv[0], cv[0]);
            sincos_acc(dy * freq, sv[1], cv[1]);
            sincos_acc(dz * freq, sv[2], cv[2]);
            #pragma unroll
            for (int d0 = 0; d0 < 3; d0++) {
                int ks = 3 + f * 6 + d0;
                int kc = ks + 3;
                dir0 = fmaf(cw0[ks], sv[d0], dir0);
                dir1 = fmaf(cw1[ks], sv[d0], dir1);
                dir2 = fmaf(cw2[ks], sv[d0], dir2);
                dir0 = fmaf(cw0[kc], cv[d0], dir0);
                dir1 = fmaf(cw1[kc], cv[d0], dir1);
                dir2 = fmaf(cw2[kc], cv[d0], dir2);
            }
        }
    }

    __syncthreads();

    // ================= Phase 2a: MFMA, K-step 0 =================
    f32x4 acc[4][8];
    #pragma unroll
    for (int mm = 0; mm < 4; ++mm)
        #pragma unroll
        for (int n0 = 0; n0 < 8; ++n0)
            acc[mm][n0] = (f32x4){0.0f, 0.0f, 0.0f, 0.0f};

    const int l = lane;
    {
        s16x8 ah[4], al4[4];
        #pragma unroll
        for (int mm = 0; mm < 4; ++mm) {
            int m = (w << 2) | mm;
            ah[mm]  = *(const s16x8*)&lds[AOFF + (m * 2 + 0) * 256 + l * 4];
            al4[mm] = *(const s16x8*)&lds[AOFF + (m * 2 + 1) * 256 + l * 4];
        }
        #pragma unroll
        for (int n0 = 0; n0 < 8; ++n0) {
            s16x8 bh = *(const s16x8*)&lds[WOFF + ((n0 * 2 + 0) * 2 + 0) * 256 + l * 4];
            s16x8 bl = *(const s16x8*)&lds[WOFF + ((n0 * 2 + 0) * 2 + 1) * 256 + l * 4];
            #pragma unroll
            for (int mm = 0; mm < 4; ++mm) {
                acc[mm][n0] = __builtin_amdgcn_mfma_f32_16x16x32_bf16(ah[mm],  bh, acc[mm][n0], 0, 0, 0);
                acc[mm][n0] = __builtin_amdgcn_mfma_f32_16x16x32_bf16(ah[mm],  bl, acc[mm][n0], 0, 0, 0);
                acc[mm][n0] = __builtin_amdgcn_mfma_f32_16x16x32_bf16(al4[mm], bh, acc[mm][n0], 0, 0, 0);
            }
        }
    }

    __syncthreads();   // all waves done reading A(s=0)

    // ================= Phase 2a.5: posenc half 2 (f5..f9), write A(s=1) ==========
    {
        float pe1[32];
        pe1[0] = f4c2;
        #pragma unroll
        for (int f = 5; f < 10; f++) {
            float freq = PI_F * (float)(1 << f);
            float s0, c0, s1, c1, s2, c2;
            sincos_acc(px * freq, s0, c0);
            sincos_acc(py * freq, s1, c1);
            sincos_acc(pz * freq, s2, c2);
            int base = 1 + (f - 5) * 6;
            pe1[base + 0] = s0; pe1[base + 1] = s1; pe1[base + 2] = s2;
            pe1[base + 3] = c0; pe1[base + 4] = c1; pe1[base + 5] = c2;
        }
        pe1[31] = 0.0f;                        // K-pad
        unsigned int pkh[16], pkl[16];
        #pragma unroll
        for (int kk = 0; kk < 16; ++kk)
            split_pack(pe1[2 * kk], pe1[2 * kk + 1], pkh[kk], pkl[kk]);
        #pragma unroll
        for (int q = 0; q < 4; ++q) {
            int lf = (q << 4) | c15;
            u32x4 vh = { pkh[q*4+0], pkh[q*4+1], pkh[q*4+2], pkh[q*4+3] };
            u32x4 vl = { pkl[q*4+0], pkl[q*4+1], pkl[q*4+2], pkl[q*4+3] };
            *(u32x4*)&lds[AOFF + (m_own * 2 + 0) * 256 + lf * 4] = vh;
            *(u32x4*)&lds[AOFF + (m_own * 2 + 1) * 256 + lf * 4] = vl;
        }
    }

    // per-lane layer-2 weights (h = n0*16 + (l&15)) — uniform scalar loads
    float pbv[8], swv[8], c0v[8], c1v[8], c2v[8];
    #pragma unroll
    for (int n0 = 0; n0 < 8; ++n0) {
        int h = n0 * 16 + (l & 15);
        pbv[n0] = pw[OFF_POSB + h];
        swv[n0] = pw[OFF_SIGW + h];
        c0v[n0] = pw[OFF_COLW + 0 * 155 + h];
        c1v[n0] = pw[OFF_COLW + 1 * 155 + h];
        c2v[n0] = pw[OFF_COLW + 2 * 155 + h];
    }

    __syncthreads();

    // ================= Phase 2b: MFMA, K-step 1 =================
    {
        s16x8 ah[4], al4[4];
        #pragma unroll
        for (int mm = 0; mm < 4; ++mm) {
            int m = (w << 2) | mm;
            ah[mm]  = *(const s16x8*)&lds[AOFF + (m * 2 + 0) * 256 + l * 4];
            al4[mm] = *(const s16x8*)&lds[AOFF + (m * 2 + 1) * 256 + l * 4];
        }
        #pragma unroll
        for (int n0 = 0; n0 < 8; ++n0) {
            s16x8 bh = *(const s16x8*)&lds[WOFF + ((n0 * 2 + 1) * 2 + 0) * 256 + l * 4];
            s16x8 bl = *(const s16x8*)&lds[WOFF + ((n0 * 2 + 1) * 2 + 1) * 256 + l * 4];
            #pragma unroll
            for (int mm = 0; mm < 4; ++mm) {
                acc[mm][n0] = __builtin_amdgcn_mfma_f32_16x16x32_bf16(ah[mm],  bh, acc[mm][n0], 0, 0, 0);
                acc[mm][n0] = __builtin_amdgcn_mfma_f32_16x16x32_bf16(ah[mm],  bl, acc[mm][n0], 0, 0, 0);
                acc[mm][n0] = __builtin_amdgcn_mfma_f32_16x16x32_bf16(al4[mm], bh, acc[mm][n0], 0, 0, 0);
            }
        }
    }

    // ================= Phase 3: bias+relu, layer 2, col-reduce, stash samples =====
    #pragma unroll
    for (int mm = 0; mm < 4; ++mm) {
        #pragma unroll
        for (int r = 0; r < 4; ++r) {
            float sp = 0.0f, p0 = 0.0f, p1 = 0.0f, p2 = 0.0f;
            #pragma unroll
            for (int n0 = 0; n0 < 8; ++n0) {
                float hv = fmaxf(acc[mm][n0][r] + pbv[n0], 0.0f);
                sp = fmaf(swv[n0], hv, sp);
                p0 = fmaf(c0v[n0], hv, p0);
                p1 = fmaf(c1v[n0], hv, p1);
                p2 = fmaf(c2v[n0], hv, p2);
            }
            #pragma unroll
            for (int ofs = 1; ofs < 16; ofs <<= 1) {
                sp += __shfl_xor(sp, ofs);
                p0 += __shfl_xor(p0, ofs);
                p1 += __shfl_xor(p1, ofs);
                p2 += __shfl_xor(p2, ofs);
            }
            if ((l & 15) == 0) {
                int sample = (mm << 4) | ((l >> 4) << 2) | r;   // = pt & 63
                int sb = SOFF + (w * 64 + sample) * 5;
                lds[sb + 0] = __builtin_bit_cast(unsigned int, sp);
                lds[sb + 1] = __builtin_bit_cast(unsigned int, p0);
                lds[sb + 2] = __builtin_bit_cast(unsigned int, p1);
                lds[sb + 3] = __builtin_bit_cast(unsigned int, p2);
            }
        }
    }

    __syncthreads();

    // ================= Phase 4: volume rendering (lane = sample) =================
    int sb = SOFF + tid * 5;
    float sigma = __builtin_bit_cast(float, lds[sb + 0]) + pw[OFF_SIGB];
    float cc0   = __builtin_bit_cast(float, lds[sb + 1]) + pw[OFF_COLB + 0] + dir0;
    float cc1   = __builtin_bit_cast(float, lds[sb + 2]) + pw[OFF_COLB + 1] + dir1;
    float cc2   = __builtin_bit_cast(float, lds[sb + 3]) + pw[OFF_COLB + 2] + dir2;

    float alpha = 1.0f - expf(-fmaxf(sigma, 0.0f) * dist);
    float tr = 1.0f - alpha + 1e-10f;
    float prod = tr;
    #pragma unroll
    for (int off = 1; off < 64; off <<= 1) {
        float up = __shfl_up(prod, off);
        if (lane >= off) prod *= up;
    }
    float T = __shfl_up(prod, 1);
    if (lane == 0) T = 1.0f;
    float wgt = alpha * T;

    float r = 1.0f / (1.0f + expf(-cc0));
    float g = 1.0f / (1.0f + expf(-cc1));
    float bl = 1.0f / (1.0f + expf(-cc2));

    float wr_ = wgt * r, wg_ = wgt * g, wb_ = wgt * bl, wz_ = wgt * z, wa_ = wgt;
    #pragma unroll
    for (int off = 32; off >= 1; off >>= 1) {
        wr_ += __shfl_xor(wr_, off);
        wg_ += __shfl_xor(wg_, off);
        wb_ += __shfl_xor(wb_, off);
        wz_ += __shfl_xor(wz_, off);
        wa_ += __shfl_xor(wa_, off);
    }

    if (lane == 0) {
        float bg = 1.0f - wa_;
        out[(b * 3 + 0) * 4096 + p] = wr_ + bg;
        out[(b * 3 + 1) * 4096 + p] = wg_ + bg;
        out[(b * 3 + 2) * 4096 + p] = wb_ + bg;
        out[NB * 3 * 4096 + b * 4096 + p] = wz_;
        out[NB * 4 * 4096 + b * 4096 + p] = wa_;
    }
}

extern "C" void kernel_launch(void* const* d_in, const int* in_sizes, int n_in,
                              void* d_out, int out_size, void* d_ws, size_t ws_size,
                              hipStream_t stream) {
    const float* params = (const float*)d_in[0];
    const float* poses  = (const float*)d_in[1];
    const float* Ks     = (const float*)d_in[2];
    float* out = (float*)d_out;
    unsigned int* ws = (unsigned int*)d_ws;
    const int use_ws = (ws_size >= (size_t)(NB * 8192 * 4)) ? 1 : 0;
    if (use_ws) {
        prep_wfrags_kernel<<<dim3(NB), dim3(256), 0, stream>>>(params, ws);
    }
    nerf_render_kernel<<<dim3(4096), dim3(256), 0, stream>>>(params, poses, Ks, out, ws, use_ws);
}